// Round 4
// baseline (115.291 us; speedup 1.0000x reference)
//
#include <hip/hip_runtime.h>
#include <cfloat>

// BottomRightPool: out[b,c,i,j] = max(x[b,c,:i+1,:j+1])
//                = cummax over H then cummax over W.
//
// Formulation: out[i] = max(out[i-1], rowscan(x[i]))   (elementwise per col)
//   - rowscan of each raw row is INDEPENDENT of all other rows -> 8 scans
//     interleave in flight, hiding the 7-deep shuffle-latency chain.
//   - the row-to-row coupling is one fmax per column (cm0/cm1 chain).
//
// One wave per 128x128 image (4096 waves = 16/CU = 4/SIMD). Lane j owns
// columns 2j,2j+1 (float2 -> 512B coalesced row). Double-buffered batches of
// 8 rows: loads for batch t+1 issue before compute of batch t -> 8 loads
// always in flight per wave (HBM latency fully pipelined).
//
// Scan uses HIP __shfl_up's self-clamp (out-of-range lanes return own value;
// fmax(s,s)=s) -> no per-step cndmask needed.

typedef float v2f __attribute__((ext_vector_type(2)));

__global__ __launch_bounds__(64)
void BottomRightPool_54357106098213_kernel(const float* __restrict__ x,
                                           float* __restrict__ out) {
    constexpr int R = 8;  // rows per batch
    const size_t img = blockIdx.x;              // b*256 + c
    const int lane = threadIdx.x;               // 0..63

    const v2f* __restrict__ xi = reinterpret_cast<const v2f*>(x) + img * 8192 + lane;
    v2f* __restrict__ oi       = reinterpret_cast<v2f*>(out)     + img * 8192 + lane;

    // Running column maxima (= out row i-1) for columns 2*lane, 2*lane+1.
    float cm0 = -FLT_MAX;
    float cm1 = -FLT_MAX;

    auto loadb = [&](v2f (&buf)[R], int t) {
        #pragma unroll
        for (int r = 0; r < R; ++r) buf[r] = xi[(t + r) * 64];
    };

    auto procb = [&](v2f (&buf)[R], int t) {
        float e[R];
        // 8 independent max-scans over the raw rows (interleaved by scheduler).
        #pragma unroll
        for (int r = 0; r < R; ++r) {
            float s = fmaxf(buf[r].x, buf[r].y);   // pairwise max of the 2 cols
            s = fmaxf(s, __shfl_up(s, 1, 64));     // self-clamped: no guard
            s = fmaxf(s, __shfl_up(s, 2, 64));
            s = fmaxf(s, __shfl_up(s, 4, 64));
            s = fmaxf(s, __shfl_up(s, 8, 64));
            s = fmaxf(s, __shfl_up(s, 16, 64));
            s = fmaxf(s, __shfl_up(s, 32, 64));
            float ex = __shfl_up(s, 1, 64);        // exclusive value
            e[r] = (lane == 0) ? -FLT_MAX : ex;
        }
        // Column-running combine + store (cheap serial fmax chain).
        #pragma unroll
        for (int r = 0; r < R; ++r) {
            float p = fmaxf(buf[r].x, buf[r].y);
            cm0 = fmaxf(cm0, fmaxf(e[r], buf[r].x));  // rowscan at col 2*lane
            cm1 = fmaxf(cm1, fmaxf(e[r], p));         // rowscan at col 2*lane+1
            v2f o; o.x = cm0; o.y = cm1;
            oi[(t + r) * 64] = o;
        }
    };

    v2f bufA[R], bufB[R];
    loadb(bufA, 0);
    for (int t = 0; t < 128; t += 2 * R) {
        loadb(bufB, t + R);               // prefetch next batch
        procb(bufA, t);                   // compute/store current
        if (t + 2 * R < 128) loadb(bufA, t + 2 * R);
        procb(bufB, t + R);
    }
}

extern "C" void kernel_launch(void* const* d_in, const int* in_sizes, int n_in,
                              void* d_out, int out_size, void* d_ws, size_t ws_size,
                              hipStream_t stream) {
    const float* x = (const float*)d_in[0];
    float* out = (float*)d_out;

    dim3 grid(16 * 256);   // one wave per (b,c) image
    dim3 block(64);
    BottomRightPool_54357106098213_kernel<<<grid, block, 0, stream>>>(x, out);
}

// Round 5
// 103.646 us; speedup vs baseline: 1.1123x; 1.1123x over previous
//
#include <hip/hip_runtime.h>
#include <cfloat>

// BottomRightPool: out[b,c,i,j] = max(x[b,c,:i+1,:j+1])
//                = cummax over H then cummax over W.
//
// Formulation: out[i] = max(out[i-1], rowscan(x[i])) per column.
// One wave per 128x128 fp32 image (4096 waves). float4 per lane ->
// one 1 KiB instruction covers TWO rows: lanes 0..31 hold row 2k
// (4 cols/lane), lanes 32..63 hold row 2k+1. Rowscans of the two rows
// are independent 32-lane segmented scans; one shfl_xor(32) merges
// them into the running column max (cm, replicated in both halves).

typedef float v4f __attribute__((ext_vector_type(4)));

__global__ __launch_bounds__(64)
void BottomRightPool_54357106098213_kernel(const float* __restrict__ x,
                                           float* __restrict__ out) {
    const size_t img = blockIdx.x;              // b*256 + c
    const int lane = threadIdx.x;               // 0..63
    const bool hi = lane >= 32;                 // hi half owns the odd row

    const v4f* __restrict__ xi = reinterpret_cast<const v4f*>(x) + img * 4096 + lane;
    v4f* __restrict__ oi       = reinterpret_cast<v4f*>(out)     + img * 4096 + lane;

    // Running column max for this lane's 4 columns (cols 4*(lane&31)..+3),
    // replicated identically in both wave halves.
    float cm0 = -FLT_MAX, cm1 = -FLT_MAX, cm2 = -FLT_MAX, cm3 = -FLT_MAX;

    #pragma unroll 4
    for (int k = 0; k < 64; ++k) {              // k covers rows 2k, 2k+1
        v4f v = __builtin_nontemporal_load(&xi[k * 64]);

        // Per-lane inclusive prefixes over the 4 owned columns.
        float p0 = v.x;
        float p1 = fmaxf(p0, v.y);
        float p2 = fmaxf(p1, v.z);
        float p3 = fmaxf(p2, v.w);

        // 32-lane segmented inclusive max-scan of p3 (self-clamped shfl_up).
        float s = p3;
        s = fmaxf(s, __shfl_up(s, 1, 32));
        s = fmaxf(s, __shfl_up(s, 2, 32));
        s = fmaxf(s, __shfl_up(s, 4, 32));
        s = fmaxf(s, __shfl_up(s, 8, 32));
        s = fmaxf(s, __shfl_up(s, 16, 32));
        // Exclusive across-lane value for this segment.
        float e = __shfl_up(s, 1, 32);
        if ((lane & 31) == 0) e = -FLT_MAX;

        // Rowscan of this row at the 4 owned columns.
        float r0 = fmaxf(e, p0);
        float r1 = fmaxf(e, p1);
        float r2 = fmaxf(e, p2);
        float r3 = s;                            // == max(e, p3)

        // Other row's rowscan at the same columns (cross-half exchange).
        float o0 = __shfl_xor(r0, 32);
        float o1 = __shfl_xor(r1, 32);
        float o2 = __shfl_xor(r2, 32);
        float o3 = __shfl_xor(r3, 32);

        // Combined two-row rowscan max (same in both halves).
        float t0 = fmaxf(r0, o0);
        float t1 = fmaxf(r1, o1);
        float t2 = fmaxf(r2, o2);
        float t3 = fmaxf(r3, o3);

        // Row 2k   (lanes<32):  out = max(cm, rs_row2k)          = max(cm, r)
        // Row 2k+1 (lanes>=32): out = max(cm, rs_2k, rs_2k+1)    = max(cm, t)
        v4f o;
        o.x = fmaxf(cm0, hi ? t0 : r0);
        o.y = fmaxf(cm1, hi ? t1 : r1);
        o.z = fmaxf(cm2, hi ? t2 : r2);
        o.w = fmaxf(cm3, hi ? t3 : r3);

        cm0 = fmaxf(cm0, t0);
        cm1 = fmaxf(cm1, t1);
        cm2 = fmaxf(cm2, t2);
        cm3 = fmaxf(cm3, t3);

        __builtin_nontemporal_store(o, &oi[k * 64]);
    }
}

extern "C" void kernel_launch(void* const* d_in, const int* in_sizes, int n_in,
                              void* d_out, int out_size, void* d_ws, size_t ws_size,
                              hipStream_t stream) {
    const float* x = (const float*)d_in[0];
    float* out = (float*)d_out;

    dim3 grid(16 * 256);   // one wave per (b,c) image
    dim3 block(64);
    BottomRightPool_54357106098213_kernel<<<grid, block, 0, stream>>>(x, out);
}